// Round 11
// baseline (21693.042 us; speedup 1.0000x reference)
//
#include <hip/hip_runtime.h>
#include <math.h>

// HMM forward: alpha_t = (alpha_{t-1} @ A) * B[:, se[t]],  out = -log(sum(alpha_{T-1}))
// N_STATES=2048, N_OBS=8192, T=8192.
//
// Structure (best-known, R5/R10):
// 64 blk x 512 thr. A in 128 f32 regs/thread (pinned; unified VGPR/AGPR file).
// Tagged-dataflow exchange: alpha published as u64 {tag:32|f32:32} agent-scope
// relaxed atomics (data==readiness, single LLC round trip); each wave polls and
// gathers only its own 256-float j-slice. ONE __syncthreads per step.
// R11 change: PIPELINED poll — two in-flight load sets checked alternately,
// halving detect granularity (vmcnt only drains to 4 per check).

#define NS    2048
#define NOBS  8192
#define TSEQ  8192
#define NBLK  64
#define NTHR  512
#define OPB   32              // output columns per block
#define JPT   128             // j-slice length per thread

typedef unsigned long long u64;
typedef unsigned int u32;

// X-macro over the 32 float4 A-fragments
#define A_LIST(X) \
  X(0)  X(1)  X(2)  X(3)  X(4)  X(5)  X(6)  X(7)  \
  X(8)  X(9)  X(10) X(11) X(12) X(13) X(14) X(15) \
  X(16) X(17) X(18) X(19) X(20) X(21) X(22) X(23) \
  X(24) X(25) X(26) X(27) X(28) X(29) X(30) X(31)

__global__ void __launch_bounds__(256) init_ws_kernel(u64* aP) {
  const int i = threadIdx.x;              // 1 block x 256 thr; 4096 u64 total
#pragma unroll
  for (int c = 0; c < 16; ++c) {
    __hip_atomic_store(&aP[i * 16 + c], 0ull, __ATOMIC_RELAXED, __HIP_MEMORY_SCOPE_AGENT);
  }
}

__global__ void __launch_bounds__(NTHR, 2) hmm_forward_kernel(
    const float* __restrict__ Pi0,
    const float* __restrict__ A,
    const float* __restrict__ B,
    const int*   __restrict__ se,
    float* __restrict__ out,
    u64*   __restrict__ aP) {          // [2][NS] tagged alpha
  __shared__ __align__(16) float alpha_sm[NS];
  __shared__ float red[2][NTHR / 64][OPB];   // [parity][wave][o] (conflict-free)

  const int tid    = threadIdx.x;
  const int blk    = blockIdx.x;
  const int w      = tid >> 6;       // wave 0..7
  const int lane   = tid & 63;
  const int h      = lane >> 5;      // half-wave
  const int o      = lane & 31;      // output slot within block
  const int i_mine = blk * OPB + o;  // owned output column
  const int jbase  = (w * 2 + h) * JPT;

  // ---- A column-slice into 32 named float4 SSA registers:
  //      Ar{k} = A[jbase+4k .. jbase+4k+3][i_mine]
#define DECLA(k) float4 Ar##k;
  A_LIST(DECLA)
#define LOADA(k) { const float* ap = A + (size_t)(jbase + 4 * k) * NS + i_mine; \
                   Ar##k.x = ap[0]; Ar##k.y = ap[NS]; Ar##k.z = ap[2 * NS]; Ar##k.w = ap[3 * NS]; }
  A_LIST(LOADA)
  // Opaque pin: asm-defined scalars cannot be refolded/remat'd into the loop.
#define PIN4(k) asm volatile("" : "+v"(Ar##k.x), "+v"(Ar##k.y), "+v"(Ar##k.z), "+v"(Ar##k.w));
  A_LIST(PIN4)

  // ---- alpha_0 = Pi0 * B[:, se[0]], computed redundantly by every block
  {
    const int s0 = se[0];
#pragma unroll
    for (int c = 0; c < 4; ++c) {
      const int i = tid * 4 + c;
      alpha_sm[i] = Pi0[i] * B[(size_t)i * NOBS + s0];
    }
  }
  __syncthreads();

  // ---- emission prefetch pipeline (publishing lanes tid<32 only):
  float bv_next = 0.f;
  if (tid < OPB) bv_next = B[(size_t)i_mine * NOBS + se[1]];
  int sidx_n2 = se[2 < TSEQ ? 2 : TSEQ - 1];

  for (int t = 1; t < TSEQ; ++t) {
    const float bv  = bv_next;
    const int   buf = t & 1;
    if (tid < OPB) bv_next = B[(size_t)i_mine * NOBS + sidx_n2];
    {
      const int tn2 = (t + 2 < TSEQ) ? (t + 2) : (TSEQ - 1);
      sidx_n2 = se[tn2];
    }

    // ---- dot over this thread's 128-long j-slice (alpha from LDS, A in regs)
    float a0 = 0.f, a1 = 0.f, a2 = 0.f, a3 = 0.f;
#define DOT(k) { const float4 av = *reinterpret_cast<const float4*>(&alpha_sm[jbase + 4 * k]); \
                 a0 = fmaf(Ar##k.x, av.x, a0); a1 = fmaf(Ar##k.y, av.y, a1); \
                 a2 = fmaf(Ar##k.z, av.z, a2); a3 = fmaf(Ar##k.w, av.w, a3); }
    A_LIST(DOT)
    float acc = (a0 + a1) + (a2 + a3);
    acc += __shfl_xor(acc, 32);        // combine the two half-wave j-slices
    if (lane < 32) red[buf][w][o] = acc;
    __syncthreads();   // the ONE barrier per step: red[buf] handoff to wave 0

    // ---- wave 0: finish reduction, apply emission, publish tagged alpha_t
    if (w == 0) {
      __builtin_amdgcn_s_setprio(1);
      float s = 0.f;
#pragma unroll
      for (int ww = 0; ww < NTHR / 64; ++ww) s += red[buf][ww][o];
      if (lane < 32) {
        const float aval = s * bv;
        const u64 pkt = (u64)__float_as_uint(aval) | ((u64)(u32)t << 32);
        __hip_atomic_store(&aP[(size_t)buf * NS + blk * OPB + o], pkt,
                           __ATOMIC_RELAXED, __HIP_MEMORY_SCOPE_AGENT);
      }
      __builtin_amdgcn_s_setprio(0);
    }

    // ---- pipelined tag-poll gather of this wave's own 256-float j-slice:
    // two in-flight load sets (A/B) of the same 4 addresses, checked
    // alternately. Checking one set drains vmcnt only to 4, so the other
    // set is already in flight -> detect granularity ~RT/2 instead of ~RT.
    {
      const u64* src = aP + (size_t)buf * NS + w * 256 + lane * 4;
      const u32 tag = (u32)t;
      u64 r0, r1, r2, r3;

#define PLD(v0, v1, v2, v3) \
      v0 = __hip_atomic_load(&src[0], __ATOMIC_RELAXED, __HIP_MEMORY_SCOPE_AGENT); \
      v1 = __hip_atomic_load(&src[1], __ATOMIC_RELAXED, __HIP_MEMORY_SCOPE_AGENT); \
      v2 = __hip_atomic_load(&src[2], __ATOMIC_RELAXED, __HIP_MEMORY_SCOPE_AGENT); \
      v3 = __hip_atomic_load(&src[3], __ATOMIC_RELAXED, __HIP_MEMORY_SCOPE_AGENT);
#define TAGOK(v0, v1, v2, v3) \
      ((u32)(v0 >> 32) == tag && (u32)(v1 >> 32) == tag && \
       (u32)(v2 >> 32) == tag && (u32)(v3 >> 32) == tag)

      u64 pa0, pa1, pa2, pa3, pb0, pb1, pb2, pb3;
      PLD(pa0, pa1, pa2, pa3)          // set A in flight
      PLD(pb0, pb1, pb2, pb3)          // set B in flight
      for (;;) {
        if (TAGOK(pa0, pa1, pa2, pa3)) {       // waits vmcnt->4; B stays out
          r0 = pa0; r1 = pa1; r2 = pa2; r3 = pa3;
          break;
        }
        PLD(pa0, pa1, pa2, pa3)                // reissue A behind B
        if (TAGOK(pb0, pb1, pb2, pb3)) {       // waits vmcnt->4; A stays out
          r0 = pb0; r1 = pb1; r2 = pb2; r3 = pb3;
          break;
        }
        PLD(pb0, pb1, pb2, pb3)                // reissue B behind A
      }

      float4 v;
      v.x = __uint_as_float((u32)r0);
      v.y = __uint_as_float((u32)r1);
      v.z = __uint_as_float((u32)r2);
      v.w = __uint_as_float((u32)r3);
      *reinterpret_cast<float4*>(&alpha_sm[w * 256 + lane * 4]) = v;
#undef PLD
#undef TAGOK
    }
    // no barrier: next dot reads only this wave's own slice
  }

  // ---- final: -log(sum(alpha_{T-1})), block 0 only
  if (blk == 0) {
    __syncthreads();   // all waves' final gathers into alpha_sm
    float s = 0.f;
#pragma unroll
    for (int c = 0; c < 4; ++c) s += alpha_sm[4 * tid + c];
#pragma unroll
    for (int off = 32; off > 0; off >>= 1) s += __shfl_xor(s, off);
    if (lane == 0) red[0][w][0] = s;
    __syncthreads();
    if (tid == 0) {
      float S = 0.f;
#pragma unroll
      for (int ww = 0; ww < NTHR / 64; ++ww) S += red[0][ww][0];
      out[0] = -logf(S);
    }
  }
}

extern "C" void kernel_launch(void* const* d_in, const int* in_sizes, int n_in,
                              void* d_out, int out_size, void* d_ws, size_t ws_size,
                              hipStream_t stream) {
  const float* Pi0 = (const float*)d_in[0];
  const float* A   = (const float*)d_in[1];
  const float* B   = (const float*)d_in[2];
  const int*   se  = (const int*)d_in[3];
  float*       out = (float*)d_out;

  // ws layout: aP = u64[2][NS] tagged alpha packets (32 KiB) at offset 0
  u64* aP = (u64*)d_ws;

  init_ws_kernel<<<1, 256, 0, stream>>>(aP);   // zero all tags (every launch)
  hmm_forward_kernel<<<NBLK, NTHR, 0, stream>>>(Pi0, A, B, se, out, aP);
}